// Round 5
// baseline (113.577 us; speedup 1.0000x reference)
//
#include <hip/hip_runtime.h>

// COO SpMM: out[r,:] = sum_e vals[e] * seq[cols[e],:], rows sorted.
// N=50000, E=1.25M, D=64, fp32 in/out.
//
// R1: 256B gathers, atomic flush             -> 56.6 us
// R2: deep double-buffer                     -> 66.5 us FAIL
// R3: interleaved streams + dword atomics    -> 270 us FAIL
// R4: float4 + ownership, scalar meta        -> 60 us
// R5: coalesced meta, 16x1KB gathers, RPS=2  -> 53 us (3.4 TB/s, occ 29%)
// R6: RPS=1, oversubscribed, depth 8         -> ~41 us (fp32 gathers)
// R7: bf16 gather table (6.4 MB)             -> harness 98.6 us
//     (fill ~45 fixed + prep ~8 + spmm ~41)
// R8: concurrent feature-split halves        -> 111 FAIL (XCD parity myth)
// R9: temporal column partition (2 phases)   -> 126 FAIL
// R10: halved vmem instrs + meta prefetch    -> 103 FAIL (no spmm gain)
//
// MODEL (fits R6/R7/R9/R10): spmm is bound by random line-TRANSACTION rate,
//   ~30 G txn/s devicewide (= 1.25M txns / 41.7 us), INDEPENDENT of txn size
//   (128 B bf16 row == 256 B fp32 row) and of table size/L2 residency
//   (12.8 MB fp32 R6 == 6.4 MB bf16 R7). 1 txn/edge is the gather floor.
//   Bytes, instruction count, and residency are all non-levers. Therefore:
// R11 (this): delete the bf16 table. Gather fp32 directly from seq
//   (R6-proven rate), prep = row_ptr only (~1.5 us, was ~8), no table
//   build, no workspace table. 32-lane subs x float2: 256 B/row paired
//   txn, x[16] float2 = 32 VGPR (total ~60 -> 8 waves/SIMD), 1 shfl +
//   2 FMA per edge per lane. Bonus: absmax 0.0625 -> ~1e-5 (exact fp32).

#define WPB 4               // waves per 256-thread block

typedef float f32x2 __attribute__((ext_vector_type(2)));

// row_start[t] = first edge e with rows[e] >= t, t in [0, n_nodes].
__global__ __launch_bounds__(256) void row_ptr_kernel(
    const int* __restrict__ rows, int* __restrict__ row_start,
    int n_edges, int n_nodes)
{
    const int e = blockIdx.x * blockDim.x + threadIdx.x;
    if (e >= n_edges) return;
    const int r    = rows[e];
    const int prev = (e == 0) ? -1 : rows[e - 1];
    for (int t = prev + 1; t <= r; ++t) row_start[t] = e;
    if (e == n_edges - 1)
        for (int t = r + 1; t <= n_nodes; ++t) row_start[t] = n_edges;
}

__global__ __launch_bounds__(256) void spmm_kernel(
    const f32x2* __restrict__ seq,        // [N][32] f32x2 = [N][64] fp32
    const float* __restrict__ vals,       // [E]
    const int*   __restrict__ cols,       // [E]
    const int*   __restrict__ row_start,  // [N+1]
    float*       __restrict__ out,        // [N, 64] fp32
    int n_nodes, int n_edges)
{
    const int lane = threadIdx.x & 63;
    const int sub  = lane >> 5;           // 32-lane sub-wave id (0..1)
    const int fl   = lane & 31;           // float2 slot: feats 2*fl, 2*fl+1
    const int ml   = lane & 15;           // meta slot within chunk of 16
    const int wave = blockIdx.x * WPB + (threadIdx.x >> 6);

    const int r = wave * 2 + sub;         // one row per 32-lane sub
    if (wave * 2 >= n_nodes) return;      // wave-uniform exit
    const bool valid = (r < n_nodes);

    int e = 0, e_end = 0;
    if (valid) {
        e     = row_start[r];
        e_end = row_start[r + 1];
    }

    f32x2 acc;
    acc.x = 0.f;
    acc.y = 0.f;

    while (__any(e < e_end)) {
        // coalesced metadata: next 16 edges of this sub
        // (lanes 16..31 of the sub load duplicates; only lanes 0..15 used
        //  as broadcast sources)
        int cidx = e + ml;
        if (cidx >= n_edges) cidx = n_edges - 1;
        const int   c = cols[cidx];
        const float v = vals[cidx];

        // 16 gathers; each sub's 32 lanes x 8 B = one contiguous 256 B
        // fp32 row = one paired-line transaction per edge (the floor).
        f32x2 x[16];
#pragma unroll
        for (int u = 0; u < 16; ++u) {
            const int cu = __shfl(c, (sub << 5) | u);   // sub-local bcast
            if (e + u < e_end)
                x[u] = seq[(cu << 5) + fl];             // 8 B: 2 fp32 feats
        }
#pragma unroll
        for (int u = 0; u < 16; ++u) {
            const float vu = __shfl(v, (sub << 5) | u);
            if (e + u < e_end) {
                acc.x = fmaf(vu, x[u].x, acc.x);
                acc.y = fmaf(vu, x[u].y, acc.y);
            }
        }
        e += 16;
    }

    // one 8 B store per lane; a sub's 32 lanes = contiguous 256 B row.
    // Also zeroes empty rows.
    if (valid)
        ((f32x2*)out)[(r << 5) + fl] = acc;
}

extern "C" void kernel_launch(void* const* d_in, const int* in_sizes, int n_in,
                              void* d_out, int out_size, void* d_ws, size_t ws_size,
                              hipStream_t stream) {
    const float* seq  = (const float*)d_in[0];
    const float* vals = (const float*)d_in[1];
    const int*   rows = (const int*)d_in[2];
    const int*   cols = (const int*)d_in[3];
    float*       out  = (float*)d_out;

    const int n_edges = in_sizes[1];            // E
    const int n_nodes = out_size / 64;          // N (out is [1,N,64])

    // ws layout: [row_start: (N+1) ints] — no table build anymore
    int* row_start = (int*)d_ws;

    {
        const int threads = 256;
        const int blocks  = (n_edges + threads - 1) / threads;
        row_ptr_kernel<<<blocks, threads, 0, stream>>>(rows, row_start,
                                                       n_edges, n_nodes);
    }
    {
        const int waves  = (n_nodes + 1) / 2;   // one row per 32-lane sub
        const int blocks = (waves + WPB - 1) / WPB;
        spmm_kernel<<<blocks, 256, 0, stream>>>(
            (const f32x2*)seq, vals, cols, row_start, out,
            n_nodes, n_edges);
    }
}